// Round 10
// baseline (161.323 us; speedup 1.0000x reference)
//
#include <hip/hip_runtime.h>
#include <stdint.h>

// Problem constants (B=8, Sq=Sk=1024, D=U=512, H=8, Dh=64)
#define ROWS 8192            // B*Sq = B*Sk
#define UDIM 512
#define SEQ  1024
#define NH   8
#define DH   64
#define SCALE 0.125f         // 1/sqrt(64)
#define LOG2E 1.44269504f
#define SC_Q (SCALE * LOG2E) // folded into Q projection epilogue

typedef unsigned short u16;
typedef __bf16 bf16_t;
typedef bf16_t bf16x8 __attribute__((ext_vector_type(8)));
typedef float f32x4 __attribute__((ext_vector_type(4)));
typedef float f32x16 __attribute__((ext_vector_type(16)));

__device__ __forceinline__ u16 f2bf(float f) {
    union { float f; uint32_t u; } v; v.f = f;
    uint32_t r = v.u + 0x7FFFu + ((v.u >> 16) & 1u);   // round-to-nearest-even
    return (u16)(r >> 16);
}

__device__ __forceinline__ float bf2f(u16 b) {
    union { uint32_t u; float f; } v; v.u = ((uint32_t)b) << 16;
    return v.f;
}

__device__ __forceinline__ uint32_t pk_bf16(float a, float b) {
#if __has_builtin(__builtin_amdgcn_cvt_pk_bf16_f32)
    typedef __bf16 bf16x2_t __attribute__((ext_vector_type(2)));
    bf16x2_t r = __builtin_amdgcn_cvt_pk_bf16_f32(a, b);
    union { bf16x2_t v; uint32_t u; } c; c.v = r;
    return c.u;
#else
    return (uint32_t)f2bf(a) | ((uint32_t)f2bf(b) << 16);
#endif
}

__device__ __forceinline__ void async_ld16(u16* lds, const u16* g) {
    __builtin_amdgcn_global_load_lds((const __attribute__((address_space(1))) void*)g,
                                     (__attribute__((address_space(3))) void*)lds, 16, 0, 0);
}

// ---------------------------------------------------------------------------
// queries/keys -> bf16 (y selects src); one wave per row
__global__ void convqk_kernel(const float* __restrict__ q, const float* __restrict__ k,
                              u16* __restrict__ qb, u16* __restrict__ kb) {
    int w = threadIdx.x >> 6, lane = threadIdx.x & 63;
    int row = blockIdx.x * 4 + w;
    const float* src = (blockIdx.y == 0) ? q : k;
    u16* dst = (blockIdx.y == 0) ? qb : kb;
    const float4* s4 = (const float4*)(src + (size_t)row * UDIM);
    ushort4* o4 = (ushort4*)(dst + (size_t)row * UDIM);
    for (int j = 0; j < 2; j++) {
        float4 v = s4[j * 64 + lane];
        ushort4 b;
        b.x = f2bf(v.x); b.y = f2bf(v.y); b.z = f2bf(v.z); b.w = f2bf(v.w);
        o4[j * 64 + lane] = b;
    }
}

// W[k][n] (512x512 f32) -> Wt[n][k] bf16, tiled via LDS. blockIdx.z selects q/k/v.
__global__ void transposeW_kernel(const float* __restrict__ Wq, const float* __restrict__ Wk,
                                  const float* __restrict__ Wv, u16* __restrict__ Wqt,
                                  u16* __restrict__ Wkt, u16* __restrict__ Wvt) {
    const float* in = (blockIdx.z == 0) ? Wq : (blockIdx.z == 1) ? Wk : Wv;
    u16* out = (blockIdx.z == 0) ? Wqt : (blockIdx.z == 1) ? Wkt : Wvt;
    __shared__ float tile[32][33];
    int k0 = blockIdx.y * 32, n0 = blockIdx.x * 32;
    int tx = threadIdx.x & 31, ty = threadIdx.x >> 5;
    for (int r = ty; r < 32; r += 8)
        tile[r][tx] = in[(size_t)(k0 + r) * UDIM + n0 + tx];
    __syncthreads();
    for (int r = ty; r < 32; r += 8)
        out[(size_t)(n0 + r) * UDIM + k0 + tx] = f2bf(tile[tx][r]);
}

// ---------------------------------------------------------------------------
// Fused QKV projection, 128x128 tile, XOR-swizzled DOUBLE-BUFFERED staging,
// prefetch at top of each k-iter, ONE barrier per iter (round-8 ordering).
// z==0 (Q): epilogue multiplies by SCALE*LOG2E. z==2 (V): Vt[b][u][sk].
#define CPAD 136   // c_s row stride in u16
__global__ __launch_bounds__(256, 3) void proj_kernel(
    const u16* __restrict__ qb, const u16* __restrict__ kb,
    const u16* __restrict__ Wqt, const u16* __restrict__ Wkt, const u16* __restrict__ Wvt,
    const float* __restrict__ bq, const float* __restrict__ bk, const float* __restrict__ bv,
    u16* __restrict__ Qp, u16* __restrict__ Kp, u16* __restrict__ Vtp)
{
    const int z = blockIdx.z;
    const u16* A = (z == 0) ? qb : kb;
    const u16* W = (z == 0) ? Wqt : (z == 1) ? Wkt : Wvt;
    const float* bias = (z == 0) ? bq : (z == 1) ? bk : bv;

    __shared__ u16 smem[128 * CPAD];    // staging: a[0]=0, a[1]=4096, b[0]=8192, b[1]=12288
    u16* c_s = smem;

    const int t = threadIdx.x;
    const int lane = t & 63, w = t >> 6;
    const int quad = lane >> 4, l15 = lane & 15;
    const int m0 = blockIdx.x * 128;
    const int n0 = blockIdx.y * 128;

    const int r0 = t >> 2;
    const int s0 = ((t & 3) ^ ((r0 >> 1) & 3)) * 8;
    const u16* Ag0 = &A[(size_t)(m0 + r0) * 512 + s0];
    const u16* Ag1 = Ag0 + (size_t)64 * 512;
    const u16* Wg0 = &W[(size_t)(n0 + r0) * 512 + s0];
    const u16* Wg1 = Wg0 + (size_t)64 * 512;
    u16* al0[2] = { &smem[0 + t * 8],     &smem[4096 + t * 8] };
    u16* al1[2] = { &smem[0 + (t + 256) * 8], &smem[4096 + (t + 256) * 8] };
    u16* bl0[2] = { &smem[8192 + t * 8],      &smem[12288 + t * 8] };
    u16* bl1[2] = { &smem[8192 + (t + 256) * 8], &smem[12288 + (t + 256) * 8] };

    int aoff[2], boff[8];
    for (int mi = 0; mi < 2; mi++) {
        int row = w * 32 + mi * 16 + l15;
        aoff[mi] = row * 32 + (quad ^ ((row >> 1) & 3)) * 8;
    }
    for (int ni = 0; ni < 8; ni++) {
        int row = ni * 16 + l15;
        boff[ni] = row * 32 + (quad ^ ((row >> 1) & 3)) * 8;
    }

    f32x4 acc[2][8];
    for (int mi = 0; mi < 2; mi++)
        for (int ni = 0; ni < 8; ni++)
            acc[mi][ni] = (f32x4){0.f, 0.f, 0.f, 0.f};

    async_ld16(al0[0], Ag0);  async_ld16(al1[0], Ag1);
    async_ld16(bl0[0], Wg0);  async_ld16(bl1[0], Wg1);
    Ag0 += 32; Ag1 += 32; Wg0 += 32; Wg1 += 32;
    __syncthreads();

    for (int kt = 0; kt < 16; kt++) {
        const int cur = kt & 1, nxt = cur ^ 1;
        if (kt < 15) {
            async_ld16(al0[nxt], Ag0);  async_ld16(al1[nxt], Ag1);
            async_ld16(bl0[nxt], Wg0);  async_ld16(bl1[nxt], Wg1);
            Ag0 += 32; Ag1 += 32; Wg0 += 32; Wg1 += 32;
        }
        const int ab = cur ? 4096 : 0, bb = cur ? 12288 : 8192;
        bf16x8 af[2], bf[8];
        for (int mi = 0; mi < 2; mi++) af[mi] = *(const bf16x8*)&smem[ab + aoff[mi]];
        for (int ni = 0; ni < 8; ni++) bf[ni] = *(const bf16x8*)&smem[bb + boff[ni]];
        for (int mi = 0; mi < 2; mi++)
            for (int ni = 0; ni < 8; ni++)
                acc[mi][ni] = __builtin_amdgcn_mfma_f32_16x16x32_bf16(af[mi], bf[ni], acc[mi][ni], 0, 0, 0);
        __syncthreads();
    }

    const float qscale = (z == 0) ? SC_Q : 1.f;
    float bvl[8];
    for (int ni = 0; ni < 8; ni++) bvl[ni] = bias[n0 + ni * 16 + l15];
    for (int mi = 0; mi < 2; mi++)
        for (int ni = 0; ni < 8; ni++)
            for (int r = 0; r < 4; r++)
                acc[mi][ni][r] = fmaxf(acc[mi][ni][r] + bvl[ni], 0.f) * qscale;

    if (z < 2) {
        for (int mi = 0; mi < 2; mi++)
            for (int ni = 0; ni < 8; ni++)
                for (int r = 0; r < 4; r++)
                    c_s[(w * 32 + mi * 16 + quad * 4 + r) * CPAD + ni * 16 + l15] =
                        f2bf(acc[mi][ni][r]);
        __syncthreads();
        u16* outp = (z == 0) ? Qp : Kp;
        for (int j = 0; j < 8; j++) {
            int c = t + j * 256;
            int mrow = c >> 4, col8 = c & 15;
            uint4 d = *(const uint4*)&c_s[mrow * CPAD + col8 * 8];
            *(uint4*)&outp[(size_t)(m0 + mrow) * 512 + n0 + col8 * 8] = d;
        }
    } else {
        for (int mi = 0; mi < 2; mi++)
            for (int ni = 0; ni < 8; ni++) {
                uint2 pk;
                pk.x = pk_bf16(acc[mi][ni][0], acc[mi][ni][1]);
                pk.y = pk_bf16(acc[mi][ni][2], acc[mi][ni][3]);
                *(uint2*)&c_s[(ni * 16 + l15) * CPAD + w * 32 + mi * 16 + quad * 4] = pk;
            }
        __syncthreads();
        const int bb2 = m0 >> 10, sk0 = m0 & 1023;
        for (int j = 0; j < 8; j++) {
            int c = t + j * 256;
            int nrow = c >> 4, col8 = c & 15;
            uint4 d = *(const uint4*)&c_s[nrow * CPAD + col8 * 8];
            *(uint4*)&Vtp[(size_t)(bb2 * 512 + n0 + nrow) * 1024 + sk0 + col8 * 8] = d;
        }
    }
}

// ---------------------------------------------------------------------------
// Flash attention, BQ=64, 32x32x16 MFMA quadrant decomposition.
// Wave w: S^T quadrant [kv-half = w&1][q-half = w>>1], PV quadrant
// [d-half = w&1][q-half = w>>1]. Each wave reads only HALF of k_s/v_s
// (12 b128/iter vs 18 for the 16x16 path), 8 MFMA/iter vs 16.
// Double-buffered K/V, prefetch at top of iter, TWO barriers per kv-iter
// (round-8 proven ordering). Coalesced bf16 O epilogue through LDS.
// A/B operand layout (32x32x16): m(or n)=lane&31, k=(lane>>5)*8+j.
// C/D layout: col=lane&31, row=(reg&3)+8*(reg>>2)+4*(lane>>5)  [m74/m101].
__global__ __launch_bounds__(256, 4) void attn_kernel(
    const u16* __restrict__ Qb, const u16* __restrict__ Kb, const u16* __restrict__ Vt,
    u16* __restrict__ Obf)
{
    __shared__ u16 k_s[2][64 * 64];   // [kv][d] swizzled, double-buffered (16 KB)
    __shared__ u16 v_s[2][64 * 64];   // [d][kv] swizzled, double-buffered (16 KB)
    __shared__ u16 p_s[64 * 64];      // [q][kv] swizzled; reused as O staging (8 KB)

    const int t = threadIdx.x, lane = t & 63, w = t >> 6;
    const int l31 = lane & 31, half = lane >> 5;
    const int wh = w & 1;               // kv-half (QK) / d-half (PV)
    const int wq = w >> 1;              // q-half
    const int fid = blockIdx.x;         // 0..1023
    const int xcd = fid & 7, j = fid >> 3;
    const int hb = xcd * 8 + (j & 7);   // 8 (b,h) groups per XCD
    const int qt = j >> 3;              // 0..15
    const int h = hb & 7, b = hb >> 3;
    const int q0 = qt * 64;

    // ---- staging addresses (pointer-incremented), same as r9 ----
    const int r0 = t >> 3;                              // 0..31
    const int s0 = ((t & 7) ^ (r0 & 7)) * 8;            // u16 offset
    const u16* kg0 = &Kb[(size_t)(b * 1024 + r0) * 512 + h * 64 + s0];
    const u16* kg1 = kg0 + (size_t)32 * 512;
    const u16* vg0 = &Vt[(size_t)(b * 512 + h * 64 + r0) * 1024 + s0];
    const u16* vg1 = vg0 + (size_t)32 * 1024;
    u16* kd0[2] = { &k_s[0][t * 8], &k_s[1][t * 8] };
    u16* kd1[2] = { &k_s[0][(t + 256) * 8], &k_s[1][(t + 256) * 8] };
    u16* vd0[2] = { &v_s[0][t * 8], &v_s[1][t * 8] };
    u16* vd1[2] = { &v_s[0][(t + 256) * 8], &v_s[1][(t + 256) * 8] };

    // ---- Q B-fragments from global: n=q=32*wq+l31, k=16t+8*half+j ----
    bf16x8 bqf[4];
    {
        int qrow = b * 1024 + q0 + 32 * wq + l31;
        for (int tk = 0; tk < 4; tk++)
            bqf[tk] = *(const bf16x8*)&Qb[(size_t)qrow * 512 + h * 64 + tk * 16 + half * 8];
    }

    // ---- hoisted LDS offsets ----
    // K/V A-frag: row = 32*wh + l31 (kv for QK, d for PV), slot = 2t+half
    int koff[4];
    {
        int row = 32 * wh + l31;
        for (int tk = 0; tk < 4; tk++)
            koff[tk] = row * 64 + (((2 * tk + half) ^ (row & 7))) * 8;
    }
    // P write (C-layout of S^T quadrant) and O-staging write share the formula:
    // row q = prow, col = 32*wh + 8g + 4*half (+r)
    const int prow = 32 * wq + l31;
    int pwoff[4], proff[4];
    for (int g = 0; g < 4; g++)
        pwoff[g] = prow * 64 + ((4 * wh + g) ^ (prow & 7)) * 8 + half * 4;
    for (int tk = 0; tk < 4; tk++)
        proff[tk] = prow * 64 + ((2 * tk + half) ^ (prow & 7)) * 8;

    float l_lane = 0.f;
    f32x16 o_acc = (f32x16){0.f,0.f,0.f,0.f,0.f,0.f,0.f,0.f,
                            0.f,0.f,0.f,0.f,0.f,0.f,0.f,0.f};

    // prologue: stage buf 0
    async_ld16(kd0[0], kg0);  async_ld16(kd1[0], kg1);
    async_ld16(vd0[0], vg0);  async_ld16(vd1[0], vg1);
    kg0 += (size_t)64 * 512; kg1 += (size_t)64 * 512;
    vg0 += 64; vg1 += 64;
    __syncthreads();

    for (int it = 0; it < 16; it++) {
        const int cur = it & 1, nxt = cur ^ 1;

        if (it < 15) {   // prefetch next kv-tile (drained at barrier B)
            async_ld16(kd0[nxt], kg0);  async_ld16(kd1[nxt], kg1);
            async_ld16(vd0[nxt], vg0);  async_ld16(vd1[nxt], vg1);
            kg0 += (size_t)64 * 512; kg1 += (size_t)64 * 512;
            vg0 += 64; vg1 += 64;
        }

        // phase 1: K (A) frags + V (A) frags from cur buffer
        bf16x8 ak[4], av[4];
        for (int tk = 0; tk < 4; tk++) {
            ak[tk] = *(const bf16x8*)&k_s[cur][koff[tk]];
            av[tk] = *(const bf16x8*)&v_s[cur][koff[tk]];
        }

        // S^T quadrant = K·Q^T (log2-scaled via Q), 4 chained 32x32x16
        f32x16 st = (f32x16){0.f,0.f,0.f,0.f,0.f,0.f,0.f,0.f,
                             0.f,0.f,0.f,0.f,0.f,0.f,0.f,0.f};
        for (int tk = 0; tk < 4; tk++)
            st = __builtin_amdgcn_mfma_f32_32x32x16_bf16(ak[tk], bqf[tk], st, 0, 0, 0);

        // p = exp2(st); accumulate l; pack to p_s (4 uint2 writes)
        for (int g = 0; g < 4; g++) {
            float p0 = exp2f(st[4 * g + 0]);
            float p1 = exp2f(st[4 * g + 1]);
            float p2 = exp2f(st[4 * g + 2]);
            float p3 = exp2f(st[4 * g + 3]);
            l_lane += (p0 + p1) + (p2 + p3);
            uint2 pk;
            pk.x = pk_bf16(p0, p1);
            pk.y = pk_bf16(p2, p3);
            *(uint2*)&p_s[pwoff[g]] = pk;
        }

        __syncthreads();   // barrier B: P visible, prefetch drained, frag reads done

        // phase 2: O^T quadrant += V^T · P (B-frags from p_s)
        for (int tk = 0; tk < 4; tk++) {
            bf16x8 bp = *(const bf16x8*)&p_s[proff[tk]];
            o_acc = __builtin_amdgcn_mfma_f32_32x32x16_bf16(av[tk], bp, o_acc, 0, 0, 0);
        }

        if (it < 15)
            __syncthreads();   // barrier A': p_s reads done before next writes
    }

    // ---- epilogue: cross-wave l reduce, normalize, coalesced bf16 store ----
    __syncthreads();                       // phase-2 p_s reads done (all waves)
    float l2 = l_lane + __shfl_xor(l_lane, 32, 64);
    float* lbuf = (float*)&k_s[0][0];      // 4*32 floats, k_s free now
    if (lane < 32) lbuf[w * 32 + l31] = l2;
    __syncthreads();
    float ltot = lbuf[w * 32 + l31] + lbuf[(w ^ 1) * 32 + l31];
    float inv = 1.f / ltot;

    // o_ls (=p_s): row q=prow, col d = 32*wh + 8g + 4*half + r  (same as pwoff)
    for (int g = 0; g < 4; g++) {
        uint2 pk;
        pk.x = pk_bf16(o_acc[4 * g + 0] * inv, o_acc[4 * g + 1] * inv);
        pk.y = pk_bf16(o_acc[4 * g + 2] * inv, o_acc[4 * g + 3] * inv);
        *(uint2*)&p_s[pwoff[g]] = pk;
    }
    __syncthreads();
    // coalesced store: 512 16B chunks, 2 per thread
    for (int rnd = 0; rnd < 2; rnd++) {
        int c = t + rnd * 256;
        int row = c >> 3, slot = c & 7;
        int phys = slot ^ (row & 7);
        uint4 d4 = *(const uint4*)&p_s[row * 64 + phys * 8];
        *(uint4*)&Obf[(size_t)(b * 1024 + q0 + row) * 512 + h * 64 + slot * 8] = d4;
    }
}

// ---------------------------------------------------------------------------
// LayerNorm epilogue with inline qmask; O is bf16. One wave per row.
__global__ void ln_kernel(const u16* __restrict__ O, const float* __restrict__ q,
                          const float* __restrict__ gamma, const float* __restrict__ beta,
                          float* __restrict__ out)
{
    int w = threadIdx.x >> 6, lane = threadIdx.x & 63;
    int row = blockIdx.x * 4 + w;
    const float4* q4 = (const float4*)(q + (size_t)row * UDIM);
    float4* o4 = (float4*)(out + (size_t)row * UDIM);

    // lane covers cols lane*8 .. lane*8+7
    float4 qq[2];
    float am = 0.f;
    for (int j = 0; j < 2; j++) {
        qq[j] = q4[2 * lane + j];
        am += fabsf(qq[j].x) + fabsf(qq[j].y) + fabsf(qq[j].z) + fabsf(qq[j].w);
    }
    uint4 ov = *(const uint4*)&O[(size_t)row * UDIM + lane * 8];
    float oo[8];
    oo[0] = bf2f((u16)(ov.x & 0xFFFF));  oo[1] = bf2f((u16)(ov.x >> 16));
    oo[2] = bf2f((u16)(ov.y & 0xFFFF));  oo[3] = bf2f((u16)(ov.y >> 16));
    oo[4] = bf2f((u16)(ov.z & 0xFFFF));  oo[5] = bf2f((u16)(ov.z >> 16));
    oo[6] = bf2f((u16)(ov.w & 0xFFFF));  oo[7] = bf2f((u16)(ov.w >> 16));

    for (int off = 32; off; off >>= 1) am += __shfl_xor(am, off, 64);
    float mask = (am > 0.f) ? 1.f : 0.f;

    float4 x[2];
    float s = 0.f, ss = 0.f;
    for (int j = 0; j < 2; j++) {
        float4 v;
        v.x = oo[4 * j + 0] * mask + qq[j].x;
        v.y = oo[4 * j + 1] * mask + qq[j].y;
        v.z = oo[4 * j + 2] * mask + qq[j].z;
        v.w = oo[4 * j + 3] * mask + qq[j].w;
        x[j] = v;
        s += v.x + v.y + v.z + v.w;
        ss += v.x * v.x + v.y * v.y + v.z * v.z + v.w * v.w;
    }
    for (int off = 32; off; off >>= 1) {
        s += __shfl_xor(s, off, 64);
        ss += __shfl_xor(ss, off, 64);
    }
    float mu = s * (1.f / 512.f);
    float var = ss * (1.f / 512.f) - mu * mu;
    float rs = rsqrtf(var + 1e-8f);
    for (int j = 0; j < 2; j++) {
        float4 g = ((const float4*)gamma)[2 * lane + j];
        float4 bb = ((const float4*)beta)[2 * lane + j];
        float4 v;
        v.x = g.x * (x[j].x - mu) * rs + bb.x;
        v.y = g.y * (x[j].y - mu) * rs + bb.y;
        v.z = g.z * (x[j].z - mu) * rs + bb.z;
        v.w = g.w * (x[j].w - mu) * rs + bb.w;
        o4[2 * lane + j] = v;
    }
}

// ---------------------------------------------------------------------------
extern "C" void kernel_launch(void* const* d_in, const int* in_sizes, int n_in,
                              void* d_out, int out_size, void* d_ws, size_t ws_size,
                              hipStream_t stream)
{
    const float* queries = (const float*)d_in[0];
    const float* keys    = (const float*)d_in[1];
    const float* Wq      = (const float*)d_in[2];
    const float* bq      = (const float*)d_in[3];
    const float* Wk      = (const float*)d_in[4];
    const float* bk      = (const float*)d_in[5];
    const float* Wv      = (const float*)d_in[6];
    const float* bv      = (const float*)d_in[7];
    const float* gamma   = (const float*)d_in[8];
    const float* beta    = (const float*)d_in[9];
    float* out = (float*)d_out;

    char* ws = (char*)d_ws;
    size_t off = 0;
    auto alloc = [&](size_t bytes) {
        void* p = ws + off;
        off += (bytes + 255) & ~(size_t)255;
        return p;
    };
    u16* qb   = (u16*)alloc((size_t)ROWS * UDIM * 2);
    u16* kb   = (u16*)alloc((size_t)ROWS * UDIM * 2);
    u16* Wqt  = (u16*)alloc((size_t)UDIM * UDIM * 2);
    u16* Wkt  = (u16*)alloc((size_t)UDIM * UDIM * 2);
    u16* Wvt  = (u16*)alloc((size_t)UDIM * UDIM * 2);
    u16* Qp   = (u16*)alloc((size_t)ROWS * UDIM * 2);
    u16* Kp   = (u16*)alloc((size_t)ROWS * UDIM * 2);
    u16* Vtp  = (u16*)alloc((size_t)ROWS * UDIM * 2);
    u16* Obf  = (u16*)alloc((size_t)ROWS * UDIM * 2);

    convqk_kernel<<<dim3(ROWS / 4, 2), 256, 0, stream>>>(queries, keys, qb, kb);
    transposeW_kernel<<<dim3(16, 16, 3), 256, 0, stream>>>(Wq, Wk, Wv, Wqt, Wkt, Wvt);
    proj_kernel<<<dim3(64, 4, 3), 256, 0, stream>>>(qb, kb, Wqt, Wkt, Wvt, bq, bk, bv, Qp, Kp, Vtp);
    attn_kernel<<<1024, 256, 0, stream>>>(Qp, Kp, Vtp, Obf);
    ln_kernel<<<ROWS / 4, 256, 0, stream>>>(Obf, queries, gamma, beta, out);
}

// Round 11
// 151.412 us; speedup vs baseline: 1.0655x; 1.0655x over previous
//
#include <hip/hip_runtime.h>
#include <stdint.h>

// Problem constants (B=8, Sq=Sk=1024, D=U=512, H=8, Dh=64)
#define ROWS 8192            // B*Sq = B*Sk
#define UDIM 512
#define SEQ  1024
#define NH   8
#define DH   64
#define SCALE 0.125f         // 1/sqrt(64)
#define LOG2E 1.44269504f
#define SC_Q (SCALE * LOG2E) // folded into Q projection epilogue

typedef unsigned short u16;
typedef __bf16 bf16_t;
typedef bf16_t bf16x8 __attribute__((ext_vector_type(8)));
typedef float f32x4 __attribute__((ext_vector_type(4)));
typedef float f32x16 __attribute__((ext_vector_type(16)));

__device__ __forceinline__ u16 f2bf(float f) {
    union { float f; uint32_t u; } v; v.f = f;
    uint32_t r = v.u + 0x7FFFu + ((v.u >> 16) & 1u);   // round-to-nearest-even
    return (u16)(r >> 16);
}

__device__ __forceinline__ float bf2f(u16 b) {
    union { uint32_t u; float f; } v; v.u = ((uint32_t)b) << 16;
    return v.f;
}

__device__ __forceinline__ uint32_t pk_bf16(float a, float b) {
#if __has_builtin(__builtin_amdgcn_cvt_pk_bf16_f32)
    typedef __bf16 bf16x2_t __attribute__((ext_vector_type(2)));
    bf16x2_t r = __builtin_amdgcn_cvt_pk_bf16_f32(a, b);
    union { bf16x2_t v; uint32_t u; } c; c.v = r;
    return c.u;
#else
    return (uint32_t)f2bf(a) | ((uint32_t)f2bf(b) << 16);
#endif
}

__device__ __forceinline__ float fast_exp2(float x) {
#if __has_builtin(__builtin_amdgcn_exp2f)
    return __builtin_amdgcn_exp2f(x);   // raw v_exp_f32 (domain is small/positive)
#else
    return exp2f(x);
#endif
}

__device__ __forceinline__ void async_ld16(u16* lds, const u16* g) {
    __builtin_amdgcn_global_load_lds((const __attribute__((address_space(1))) void*)g,
                                     (__attribute__((address_space(3))) void*)lds, 16, 0, 0);
}

// ---------------------------------------------------------------------------
// W[k][n] (512x512 f32) -> Wt[n][k] bf16, tiled via LDS. blockIdx.z selects q/k/v.
__global__ void transposeW_kernel(const float* __restrict__ Wq, const float* __restrict__ Wk,
                                  const float* __restrict__ Wv, u16* __restrict__ Wqt,
                                  u16* __restrict__ Wkt, u16* __restrict__ Wvt) {
    const float* in = (blockIdx.z == 0) ? Wq : (blockIdx.z == 1) ? Wk : Wv;
    u16* out = (blockIdx.z == 0) ? Wqt : (blockIdx.z == 1) ? Wkt : Wvt;
    __shared__ float tile[32][33];
    int k0 = blockIdx.y * 32, n0 = blockIdx.x * 32;
    int tx = threadIdx.x & 31, ty = threadIdx.x >> 5;
    for (int r = ty; r < 32; r += 8)
        tile[r][tx] = in[(size_t)(k0 + r) * UDIM + n0 + tx];
    __syncthreads();
    for (int r = ty; r < 32; r += 8)
        out[(size_t)(n0 + r) * UDIM + k0 + tx] = f2bf(tile[tx][r]);
}

// ---------------------------------------------------------------------------
// Fused QKV projection reading FP32 activations directly (conv kernel
// eliminated). A staged as fp32 (16 KB/tile) via global_load_lds w=16
// (4 floats/chunk), packed to bf16 at fragment-read time (cvt_pk_bf16).
// B = pre-transposed bf16 W. 128x128 tile, double-buffered, prefetch at
// top of iter, ONE barrier per iter (round-8 ordering).
// LDS: A0@0 A1@8192 B0@16384 B1@20480 (u16 idx); epilogue reuses as c_s.
// z==0 (Q): epilogue multiplies by SCALE*LOG2E. z==2 (V): Vt[b][u][sk].
#define CPAD 136   // c_s row stride in u16
__global__ __launch_bounds__(256, 3) void proj_kernel(
    const float* __restrict__ queries, const float* __restrict__ keys,
    const u16* __restrict__ Wqt, const u16* __restrict__ Wkt, const u16* __restrict__ Wvt,
    const float* __restrict__ bq, const float* __restrict__ bk, const float* __restrict__ bv,
    u16* __restrict__ Qp, u16* __restrict__ Kp, u16* __restrict__ Vtp)
{
    const int z = blockIdx.z;
    const float* A = (z == 0) ? queries : keys;
    const u16* W = (z == 0) ? Wqt : (z == 1) ? Wkt : Wvt;
    const float* bias = (z == 0) ? bq : (z == 1) ? bk : bv;

    __shared__ u16 smem[24576];         // 48 KB
    float* smf = (float*)smem;          // fp32 view for A buffers
    u16* c_s = smem;                    // epilogue view (128 x CPAD)

    const int t = threadIdx.x;
    const int lane = t & 63, w = t >> 6;
    const int quad = lane >> 4, l15 = lane & 15;
    const int m0 = blockIdx.x * 128;
    const int n0 = blockIdx.y * 128;

    // ---- A staging (fp32): 1024 chunks of 16B, 4 per thread ----
    const float* Agp[4];
    u16* Adst[4][2];
    for (int i = 0; i < 4; i++) {
        int c = t + i * 256;
        int row = c >> 3, jg = (c & 7) ^ (row & 7);
        Agp[i] = &A[(size_t)(m0 + row) * 512 + jg * 4];
        Adst[i][0] = &smem[c * 8];
        Adst[i][1] = &smem[8192 + c * 8];
    }
    // ---- B staging (bf16): 512 chunks, 2 per thread ----
    const u16* Wgp[2];
    u16* Bdst[2][2];
    for (int i = 0; i < 2; i++) {
        int c = t + i * 256;
        int row = c >> 2, jg = (c & 3) ^ ((row >> 1) & 3);
        Wgp[i] = &W[(size_t)(n0 + row) * 512 + jg * 8];
        Bdst[i][0] = &smem[16384 + c * 8];
        Bdst[i][1] = &smem[20480 + c * 8];
    }

    // ---- hoisted fragment offsets ----
    int aoffF[2][2];   // float indices into A buffer
    for (int mi = 0; mi < 2; mi++) {
        int row = w * 32 + mi * 16 + l15;
        int p0 = (2 * quad) ^ (row & 7);
        int p1 = (2 * quad + 1) ^ (row & 7);
        aoffF[mi][0] = row * 32 + p0 * 4;
        aoffF[mi][1] = row * 32 + p1 * 4;
    }
    int boff[8];
    for (int ni = 0; ni < 8; ni++) {
        int row = ni * 16 + l15;
        boff[ni] = row * 32 + (quad ^ ((row >> 1) & 3)) * 8;
    }

    f32x4 acc[2][8];
    for (int mi = 0; mi < 2; mi++)
        for (int ni = 0; ni < 8; ni++)
            acc[mi][ni] = (f32x4){0.f, 0.f, 0.f, 0.f};

    // prologue: stage k-tile 0 into buf 0
    for (int i = 0; i < 4; i++) async_ld16(Adst[i][0], (const u16*)Agp[i]);
    for (int i = 0; i < 2; i++) async_ld16(Bdst[i][0], Wgp[i]);
    for (int i = 0; i < 4; i++) Agp[i] += 32;
    for (int i = 0; i < 2; i++) Wgp[i] += 32;
    __syncthreads();

    for (int kt = 0; kt < 16; kt++) {
        const int cur = kt & 1, nxt = cur ^ 1;
        if (kt < 15) {
            for (int i = 0; i < 4; i++) async_ld16(Adst[i][nxt], (const u16*)Agp[i]);
            for (int i = 0; i < 2; i++) async_ld16(Bdst[i][nxt], Wgp[i]);
            for (int i = 0; i < 4; i++) Agp[i] += 32;
            for (int i = 0; i < 2; i++) Wgp[i] += 32;
        }
        const int abF = cur ? 4096 : 0;        // float idx base of A buffer
        const int bbU = cur ? 20480 : 16384;   // u16 idx base of B buffer

        bf16x8 af[2], bf[8];
        for (int mi = 0; mi < 2; mi++) {
            f32x4 x0 = *(const f32x4*)&smf[abF + aoffF[mi][0]];
            f32x4 x1 = *(const f32x4*)&smf[abF + aoffF[mi][1]];
            union { bf16x8 v; uint32_t u[4]; } pk;
            pk.u[0] = pk_bf16(x0[0], x0[1]);
            pk.u[1] = pk_bf16(x0[2], x0[3]);
            pk.u[2] = pk_bf16(x1[0], x1[1]);
            pk.u[3] = pk_bf16(x1[2], x1[3]);
            af[mi] = pk.v;
        }
        for (int ni = 0; ni < 8; ni++) bf[ni] = *(const bf16x8*)&smem[bbU + boff[ni]];
        for (int mi = 0; mi < 2; mi++)
            for (int ni = 0; ni < 8; ni++)
                acc[mi][ni] = __builtin_amdgcn_mfma_f32_16x16x32_bf16(af[mi], bf[ni], acc[mi][ni], 0, 0, 0);
        __syncthreads();
    }

    const float qscale = (z == 0) ? SC_Q : 1.f;
    float bvl[8];
    for (int ni = 0; ni < 8; ni++) bvl[ni] = bias[n0 + ni * 16 + l15];
    for (int mi = 0; mi < 2; mi++)
        for (int ni = 0; ni < 8; ni++)
            for (int r = 0; r < 4; r++)
                acc[mi][ni][r] = fmaxf(acc[mi][ni][r] + bvl[ni], 0.f) * qscale;

    if (z < 2) {
        for (int mi = 0; mi < 2; mi++)
            for (int ni = 0; ni < 8; ni++)
                for (int r = 0; r < 4; r++)
                    c_s[(w * 32 + mi * 16 + quad * 4 + r) * CPAD + ni * 16 + l15] =
                        f2bf(acc[mi][ni][r]);
        __syncthreads();
        u16* outp = (z == 0) ? Qp : Kp;
        for (int j = 0; j < 8; j++) {
            int c = t + j * 256;
            int mrow = c >> 4, col8 = c & 15;
            uint4 d = *(const uint4*)&c_s[mrow * CPAD + col8 * 8];
            *(uint4*)&outp[(size_t)(m0 + mrow) * 512 + n0 + col8 * 8] = d;
        }
    } else {
        for (int mi = 0; mi < 2; mi++)
            for (int ni = 0; ni < 8; ni++) {
                uint2 pk;
                pk.x = pk_bf16(acc[mi][ni][0], acc[mi][ni][1]);
                pk.y = pk_bf16(acc[mi][ni][2], acc[mi][ni][3]);
                *(uint2*)&c_s[(ni * 16 + l15) * CPAD + w * 32 + mi * 16 + quad * 4] = pk;
            }
        __syncthreads();
        const int bb2 = m0 >> 10, sk0 = m0 & 1023;
        for (int j = 0; j < 8; j++) {
            int c = t + j * 256;
            int nrow = c >> 4, col8 = c & 15;
            uint4 d = *(const uint4*)&c_s[nrow * CPAD + col8 * 8];
            *(uint4*)&Vtp[(size_t)(bb2 * 512 + n0 + nrow) * 1024 + sk0 + col8 * 8] = d;
        }
    }
}

// ---------------------------------------------------------------------------
// Flash attention, BQ=64, 32x32x16 MFMA quadrants (round-10 verified),
// with raw-v_exp exp2. Double-buffered K/V, prefetch at top of iter, TWO
// barriers per kv-iter (round-8 proven ordering). Coalesced bf16 O epilogue.
__global__ __launch_bounds__(256, 4) void attn_kernel(
    const u16* __restrict__ Qb, const u16* __restrict__ Kb, const u16* __restrict__ Vt,
    u16* __restrict__ Obf)
{
    __shared__ u16 k_s[2][64 * 64];   // [kv][d] swizzled, double-buffered (16 KB)
    __shared__ u16 v_s[2][64 * 64];   // [d][kv] swizzled, double-buffered (16 KB)
    __shared__ u16 p_s[64 * 64];      // [q][kv] swizzled; reused as O staging (8 KB)

    const int t = threadIdx.x, lane = t & 63, w = t >> 6;
    const int l31 = lane & 31, half = lane >> 5;
    const int wh = w & 1;               // kv-half (QK) / d-half (PV)
    const int wq = w >> 1;              // q-half
    const int fid = blockIdx.x;         // 0..1023
    const int xcd = fid & 7, j = fid >> 3;
    const int hb = xcd * 8 + (j & 7);   // 8 (b,h) groups per XCD
    const int qt = j >> 3;              // 0..15
    const int h = hb & 7, b = hb >> 3;
    const int q0 = qt * 64;

    const int r0 = t >> 3;                              // 0..31
    const int s0 = ((t & 7) ^ (r0 & 7)) * 8;            // u16 offset
    const u16* kg0 = &Kb[(size_t)(b * 1024 + r0) * 512 + h * 64 + s0];
    const u16* kg1 = kg0 + (size_t)32 * 512;
    const u16* vg0 = &Vt[(size_t)(b * 512 + h * 64 + r0) * 1024 + s0];
    const u16* vg1 = vg0 + (size_t)32 * 1024;
    u16* kd0[2] = { &k_s[0][t * 8], &k_s[1][t * 8] };
    u16* kd1[2] = { &k_s[0][(t + 256) * 8], &k_s[1][(t + 256) * 8] };
    u16* vd0[2] = { &v_s[0][t * 8], &v_s[1][t * 8] };
    u16* vd1[2] = { &v_s[0][(t + 256) * 8], &v_s[1][(t + 256) * 8] };

    // Q B-fragments from global: n=q=32*wq+l31, k=16t+8*half+j
    bf16x8 bqf[4];
    {
        int qrow = b * 1024 + q0 + 32 * wq + l31;
        for (int tk = 0; tk < 4; tk++)
            bqf[tk] = *(const bf16x8*)&Qb[(size_t)qrow * 512 + h * 64 + tk * 16 + half * 8];
    }

    int koff[4];
    {
        int row = 32 * wh + l31;
        for (int tk = 0; tk < 4; tk++)
            koff[tk] = row * 64 + (((2 * tk + half) ^ (row & 7))) * 8;
    }
    const int prow = 32 * wq + l31;
    int pwoff[4], proff[4];
    for (int g = 0; g < 4; g++)
        pwoff[g] = prow * 64 + ((4 * wh + g) ^ (prow & 7)) * 8 + half * 4;
    for (int tk = 0; tk < 4; tk++)
        proff[tk] = prow * 64 + ((2 * tk + half) ^ (prow & 7)) * 8;

    float l_lane = 0.f;
    f32x16 o_acc = (f32x16){0.f,0.f,0.f,0.f,0.f,0.f,0.f,0.f,
                            0.f,0.f,0.f,0.f,0.f,0.f,0.f,0.f};

    async_ld16(kd0[0], kg0);  async_ld16(kd1[0], kg1);
    async_ld16(vd0[0], vg0);  async_ld16(vd1[0], vg1);
    kg0 += (size_t)64 * 512; kg1 += (size_t)64 * 512;
    vg0 += 64; vg1 += 64;
    __syncthreads();

    for (int it = 0; it < 16; it++) {
        const int cur = it & 1, nxt = cur ^ 1;

        if (it < 15) {
            async_ld16(kd0[nxt], kg0);  async_ld16(kd1[nxt], kg1);
            async_ld16(vd0[nxt], vg0);  async_ld16(vd1[nxt], vg1);
            kg0 += (size_t)64 * 512; kg1 += (size_t)64 * 512;
            vg0 += 64; vg1 += 64;
        }

        bf16x8 ak[4], av[4];
        for (int tk = 0; tk < 4; tk++) {
            ak[tk] = *(const bf16x8*)&k_s[cur][koff[tk]];
            av[tk] = *(const bf16x8*)&v_s[cur][koff[tk]];
        }

        f32x16 st = (f32x16){0.f,0.f,0.f,0.f,0.f,0.f,0.f,0.f,
                             0.f,0.f,0.f,0.f,0.f,0.f,0.f,0.f};
        for (int tk = 0; tk < 4; tk++)
            st = __builtin_amdgcn_mfma_f32_32x32x16_bf16(ak[tk], bqf[tk], st, 0, 0, 0);

        for (int g = 0; g < 4; g++) {
            float p0 = fast_exp2(st[4 * g + 0]);
            float p1 = fast_exp2(st[4 * g + 1]);
            float p2 = fast_exp2(st[4 * g + 2]);
            float p3 = fast_exp2(st[4 * g + 3]);
            l_lane += (p0 + p1) + (p2 + p3);
            uint2 pk;
            pk.x = pk_bf16(p0, p1);
            pk.y = pk_bf16(p2, p3);
            *(uint2*)&p_s[pwoff[g]] = pk;
        }

        __syncthreads();   // barrier B: P visible, prefetch drained, frag reads done

        for (int tk = 0; tk < 4; tk++) {
            bf16x8 bp = *(const bf16x8*)&p_s[proff[tk]];
            o_acc = __builtin_amdgcn_mfma_f32_32x32x16_bf16(av[tk], bp, o_acc, 0, 0, 0);
        }

        if (it < 15)
            __syncthreads();   // barrier A': p_s reads done before next writes
    }

    // epilogue: cross-wave l reduce, normalize, coalesced bf16 store
    __syncthreads();
    float l2 = l_lane + __shfl_xor(l_lane, 32, 64);
    float* lbuf = (float*)&k_s[0][0];
    if (lane < 32) lbuf[w * 32 + l31] = l2;
    __syncthreads();
    float ltot = lbuf[w * 32 + l31] + lbuf[(w ^ 1) * 32 + l31];
    float inv = 1.f / ltot;

    for (int g = 0; g < 4; g++) {
        uint2 pk;
        pk.x = pk_bf16(o_acc[4 * g + 0] * inv, o_acc[4 * g + 1] * inv);
        pk.y = pk_bf16(o_acc[4 * g + 2] * inv, o_acc[4 * g + 3] * inv);
        *(uint2*)&p_s[pwoff[g]] = pk;
    }
    __syncthreads();
    for (int rnd = 0; rnd < 2; rnd++) {
        int c = t + rnd * 256;
        int row = c >> 3, slot = c & 7;
        int phys = slot ^ (row & 7);
        uint4 d4 = *(const uint4*)&p_s[row * 64 + phys * 8];
        *(uint4*)&Obf[(size_t)(b * 1024 + q0 + row) * 512 + h * 64 + slot * 8] = d4;
    }
}

// ---------------------------------------------------------------------------
// LayerNorm epilogue with inline qmask; O is bf16. One wave per row.
__global__ void ln_kernel(const u16* __restrict__ O, const float* __restrict__ q,
                          const float* __restrict__ gamma, const float* __restrict__ beta,
                          float* __restrict__ out)
{
    int w = threadIdx.x >> 6, lane = threadIdx.x & 63;
    int row = blockIdx.x * 4 + w;
    const float4* q4 = (const float4*)(q + (size_t)row * UDIM);
    float4* o4 = (float4*)(out + (size_t)row * UDIM);

    float4 qq[2];
    float am = 0.f;
    for (int j = 0; j < 2; j++) {
        qq[j] = q4[2 * lane + j];
        am += fabsf(qq[j].x) + fabsf(qq[j].y) + fabsf(qq[j].z) + fabsf(qq[j].w);
    }
    uint4 ov = *(const uint4*)&O[(size_t)row * UDIM + lane * 8];
    float oo[8];
    oo[0] = bf2f((u16)(ov.x & 0xFFFF));  oo[1] = bf2f((u16)(ov.x >> 16));
    oo[2] = bf2f((u16)(ov.y & 0xFFFF));  oo[3] = bf2f((u16)(ov.y >> 16));
    oo[4] = bf2f((u16)(ov.z & 0xFFFF));  oo[5] = bf2f((u16)(ov.z >> 16));
    oo[6] = bf2f((u16)(ov.w & 0xFFFF));  oo[7] = bf2f((u16)(ov.w >> 16));

    for (int off = 32; off; off >>= 1) am += __shfl_xor(am, off, 64);
    float mask = (am > 0.f) ? 1.f : 0.f;

    float4 x[2];
    float s = 0.f, ss = 0.f;
    for (int j = 0; j < 2; j++) {
        float4 v;
        v.x = oo[4 * j + 0] * mask + qq[j].x;
        v.y = oo[4 * j + 1] * mask + qq[j].y;
        v.z = oo[4 * j + 2] * mask + qq[j].z;
        v.w = oo[4 * j + 3] * mask + qq[j].w;
        x[j] = v;
        s += v.x + v.y + v.z + v.w;
        ss += v.x * v.x + v.y * v.y + v.z * v.z + v.w * v.w;
    }
    for (int off = 32; off; off >>= 1) {
        s += __shfl_xor(s, off, 64);
        ss += __shfl_xor(ss, off, 64);
    }
    float mu = s * (1.f / 512.f);
    float var = ss * (1.f / 512.f) - mu * mu;
    float rs = rsqrtf(var + 1e-8f);
    for (int j = 0; j < 2; j++) {
        float4 g = ((const float4*)gamma)[2 * lane + j];
        float4 bb = ((const float4*)beta)[2 * lane + j];
        float4 v;
        v.x = g.x * (x[j].x - mu) * rs + bb.x;
        v.y = g.y * (x[j].y - mu) * rs + bb.y;
        v.z = g.z * (x[j].z - mu) * rs + bb.z;
        v.w = g.w * (x[j].w - mu) * rs + bb.w;
        o4[2 * lane + j] = v;
    }
}

// ---------------------------------------------------------------------------
extern "C" void kernel_launch(void* const* d_in, const int* in_sizes, int n_in,
                              void* d_out, int out_size, void* d_ws, size_t ws_size,
                              hipStream_t stream)
{
    const float* queries = (const float*)d_in[0];
    const float* keys    = (const float*)d_in[1];
    const float* Wq      = (const float*)d_in[2];
    const float* bq      = (const float*)d_in[3];
    const float* Wk      = (const float*)d_in[4];
    const float* bk      = (const float*)d_in[5];
    const float* Wv      = (const float*)d_in[6];
    const float* bv      = (const float*)d_in[7];
    const float* gamma   = (const float*)d_in[8];
    const float* beta    = (const float*)d_in[9];
    float* out = (float*)d_out;

    char* ws = (char*)d_ws;
    size_t off = 0;
    auto alloc = [&](size_t bytes) {
        void* p = ws + off;
        off += (bytes + 255) & ~(size_t)255;
        return p;
    };
    u16* Wqt  = (u16*)alloc((size_t)UDIM * UDIM * 2);
    u16* Wkt  = (u16*)alloc((size_t)UDIM * UDIM * 2);
    u16* Wvt  = (u16*)alloc((size_t)UDIM * UDIM * 2);
    u16* Qp   = (u16*)alloc((size_t)ROWS * UDIM * 2);
    u16* Kp   = (u16*)alloc((size_t)ROWS * UDIM * 2);
    u16* Vtp  = (u16*)alloc((size_t)ROWS * UDIM * 2);
    u16* Obf  = (u16*)alloc((size_t)ROWS * UDIM * 2);

    transposeW_kernel<<<dim3(16, 16, 3), 256, 0, stream>>>(Wq, Wk, Wv, Wqt, Wkt, Wvt);
    proj_kernel<<<dim3(64, 4, 3), 256, 0, stream>>>(queries, keys, Wqt, Wkt, Wvt,
                                                    bq, bk, bv, Qp, Kp, Vtp);
    attn_kernel<<<1024, 256, 0, stream>>>(Qp, Kp, Vtp, Obf);
    ln_kernel<<<ROWS / 4, 256, 0, stream>>>(Obf, queries, gamma, beta, out);
}